// Round 18
// baseline (358.546 us; speedup 1.0000x reference)
//
#include <hip/hip_runtime.h>
#include <hip/hip_bf16.h>
#include <hip/hip_fp8.h>

#define B_    1024
#define C_    896
#define N_    49
#define NN    2401
#define HD    128
#define NH    7
#define CQK   1792      // q,k cols of QK (V never used)
#define KTOP  2160      // int(2401*0.9)
#define SCALE 0.08838834764831845f  // 128^-0.5

typedef unsigned short ushort_t;
typedef unsigned char u8;
typedef unsigned int u32;
typedef float f32x4  __attribute__((ext_vector_type(4)));
typedef int   i32x4  __attribute__((ext_vector_type(4)));
typedef int   i32x8  __attribute__((ext_vector_type(8)));

#define SCALE1 0x7F7F7F7F   // e8m0 = 127 in all bytes -> x1.0

__device__ __forceinline__ u8 f2fp8(float f) {
  __hip_fp8_e4m3 q(f);                      // OCP e4m3fn on gfx950
  return (u8)q.__x;
}

__device__ __forceinline__ void gload16(const void* g, void* l) {
  __builtin_amdgcn_global_load_lds((const __attribute__((address_space(1))) u32*)g,
                                   (__attribute__((address_space(3))) u32*)l, 16, 0, 0);
}

// ---------------- kernel 1: W (first 1792 rows) -> fp8 e4m3 ----------------
__global__ void k_convW(const float* __restrict__ W, u8* __restrict__ Wf8) {
  int i = blockIdx.x * 256 + threadIdx.x;          // quad index
  if (i >= CQK * C_ / 4) return;
  const float* wp = W + (size_t)i * 4;
  u32 r = (u32)f2fp8(wp[0]) | ((u32)f2fp8(wp[1]) << 8)
        | ((u32)f2fp8(wp[2]) << 16) | ((u32)f2fp8(wp[3]) << 24);
  ((u32*)Wf8)[i] = r;
}

// ---------------- kernel 2: transpose x -> tokens fp8 [MG][896] ----------------
__global__ __launch_bounds__(256) void k_tr(const float* __restrict__ x,
                                            u8* __restrict__ tokens,
                                            int boff) {
  __shared__ u8 T2[49][80];
  const int bid = blockIdx.x;
  const int bl  = bid / 14;            // local batch
  const int cg  = bid % 14;            // c-group (64 channels)
  const float* xb = x + (size_t)(boff + bl) * (C_ * N_) + (size_t)cg * 64 * N_;
  for (int idx = threadIdx.x; idx < 784; idx += 256) {   // 64*49/4 float4s
    float4 f = ((const float4*)xb)[idx];
    int e0 = idx * 4;
#pragma unroll
    for (int u = 0; u < 4; ++u) {
      int e = e0 + u;
      int ci = e / 49, n = e - ci * 49;
      float v = (u == 0) ? f.x : (u == 1) ? f.y : (u == 2) ? f.z : f.w;
      T2[n][ci] = f2fp8(v);
    }
  }
  __syncthreads();
  u8* tb = tokens + (size_t)(bl * 49) * C_ + cg * 64;
  for (int idx = threadIdx.x; idx < 49 * 4; idx += 256) {
    int n = idx >> 2, c16 = (idx & 3) * 16;
    *(uint4*)(tb + (size_t)n * C_ + c16) = *(const uint4*)&T2[n][c16];
  }
}

// ---------------- kernel 3: GEMM QK = tokens * Wf8^T (MX fp8, unit scales) ----------------
// 128x128 tile, BK=128, 8 waves (wm M-half 64, wn N-quarter 32), wave-tile 64x32.
// A: LDS-staged (2-slot 32 KB static, swizzled) -> 4 blocks/CU = 8 waves/SIMD.
// B: direct global->register, double-buffered across K-iterations (L2-resident 1.6 MB).
// mfma_scale_f32_16x16x128_f8f6f4, unit e8m0 scales (bit-identical to plain fp8).
__global__ __launch_bounds__(512, 4) void k_gemm(const u8* __restrict__ tokens,
                                                 const u8* __restrict__ Wf8,
                                                 u8* __restrict__ QK,
                                                 int MG) {
  __shared__ u8 sA[2][16384];   // [slot][128 rows][128 B]

  // bijective XCD-chunk swizzle (m204)
  const int nwg = gridDim.x;
  const int q8 = nwg >> 3, r8 = nwg & 7;
  const int xcd = blockIdx.x & 7, idx8 = blockIdx.x >> 3;
  const int tile = (xcd < r8 ? xcd * (q8 + 1) : r8 * (q8 + 1) + (xcd - r8) * q8) + idx8;

  const int mt = tile / 14, nt = tile - mt * 14;
  const int m0 = mt * 128, n0 = nt * 128;

  const int t = threadIdx.x;
  const int w = t >> 6, l = t & 63;
  const int lrow = l & 15, hi = l >> 4;
  const int wm = w & 1, wn = w >> 1;   // wm: M-half (64), wn: N-quarter (32)

  // stage-side (A only): thread t covers rows (t>>3)+u*64, 16B piece (t&7), swizzled src
  const int srow8 = t >> 3;                        // 0..63
  const int sp16  = ((t & 7) ^ (srow8 & 7)) * 16;  // pre-swizzled source byte col
  const u8* aSrc[2];
#pragma unroll
  for (int u = 0; u < 2; ++u) {
    int ar = m0 + u * 64 + srow8; if (ar >= MG) ar = MG - 1;
    aSrc[u] = tokens + (size_t)ar * C_ + sp16;
  }
  u8* ldsA = &sA[0][0] + t * 16;

  // B direct-from-global per-lane bases (R11/R12-verified fragment address pattern)
  const u8* bp[2];
#pragma unroll
  for (int n = 0; n < 2; ++n)
    bp[n] = Wf8 + (size_t)(n0 + wn * 32 + n * 16 + lrow) * C_ + hi * 32;

  // frag-side A: lane's low 16B = logical piece 2hi -> phys p0; high 16B = p0^16
  const int key = lrow & 7;
  const int p0 = ((2 * hi) ^ key) * 16;
  const int aRow0 = (wm * 64 + lrow) * 128;   // + m*16*128

  f32x4 acc[4][2];
#pragma unroll
  for (int m = 0; m < 4; ++m)
#pragma unroll
    for (int n = 0; n < 2; ++n) acc[m][n] = (f32x4){0.f, 0.f, 0.f, 0.f};

  auto STAGE = [&](int kt) {
    const int so = (kt & 1) * 16384;
    const int kc = kt * 128;
#pragma unroll
    for (int u = 0; u < 2; ++u)
      gload16(aSrc[u] + kc, ldsA + so + u * 8192);
  };
  auto LD32A = [&](const u8* base) -> i32x8 {
    i32x8 v;
    *(i32x4*)&v       = *(const i32x4*)(base + p0);
    *((i32x4*)&v + 1) = *(const i32x4*)(base + (p0 ^ 16));
    return v;
  };
  auto LDB = [&](int kt, i32x8 bo[2]) {
#pragma unroll
    for (int n = 0; n < 2; ++n) {
      *(i32x4*)&bo[n]       = *(const i32x4*)(bp[n] + kt * 128);
      *((i32x4*)&bo[n] + 1) = *(const i32x4*)(bp[n] + kt * 128 + 16);
    }
  };

  i32x8 bcur[2], bnext[2];
  STAGE(0);
  LDB(0, bcur);
  __syncthreads();

#pragma unroll 1
  for (int kt = 0; kt < 7; ++kt) {
    const int so = (kt & 1) * 16384;
    if (kt < 6) {
      STAGE(kt + 1);
      LDB(kt + 1, bnext);
    }
    i32x8 av[4];
#pragma unroll
    for (int m = 0; m < 4; ++m)
      av[m] = LD32A(&sA[0][0] + so + aRow0 + m * 2048);
    __builtin_amdgcn_s_setprio(1);
#pragma unroll
    for (int m = 0; m < 4; ++m)
#pragma unroll
      for (int n = 0; n < 2; ++n)
        acc[m][n] = __builtin_amdgcn_mfma_scale_f32_16x16x128_f8f6f4(
            av[m], bcur[n], acc[m][n],
            0 /*cbsz: fp8*/, 0 /*blgp: fp8*/,
            0, SCALE1, 0, SCALE1);
    __builtin_amdgcn_s_setprio(0);
    __syncthreads();   // drains A-staging (and bnext); other resident blocks compute
    bcur[0] = bnext[0];
    bcur[1] = bnext[1];
  }

  // epilogue: D col=lane&15, row=(lane>>4)*4+r; fold SCALE into Q cols (<896); QK fp8
#pragma unroll
  for (int m = 0; m < 4; ++m) {
#pragma unroll
    for (int n = 0; n < 2; ++n) {
      int gcol = n0 + wn * 32 + n * 16 + lrow;
      float sc = (gcol < C_) ? SCALE : 1.0f;
#pragma unroll
      for (int r = 0; r < 4; ++r) {
        int grow = m0 + wm * 64 + m * 16 + hi * 4 + r;
        if (grow < MG)
          QK[(size_t)grow * CQK + gcol] = f2fp8(acc[m][n][r] * sc);
      }
    }
  }
}

// ---------------- kernel 4: logits+softmax+min+select+rollout, one WAVE per batch ----------------
__global__ __launch_bounds__(256) void k_attn2(const u8* __restrict__ QK,
                                               float* __restrict__ att,
                                               u32* __restrict__ gmask,
                                               float* __restrict__ fused0,
                                               int boff) {
  __shared__ u32 lmask[76];
  const int tid  = threadIdx.x;
  const int wid  = tid >> 6;
  const int lane = tid & 63;
  const int lrow = lane & 15;
  const int hi   = lane >> 4;
  const int lk   = hi * 8;
  const int bloc = blockIdx.x * 4 + wid;
  const int bg   = boff + bloc;
  const f32x4 z4 = {0.f, 0.f, 0.f, 0.f};

  for (int p = tid; p < 76; p += 256) lmask[p] = 0u;
  __syncthreads();

  const u8* Qb = QK + (size_t)bloc * 49 * CQK;
  const u8* Kb = Qb + C_;

  int rr[4];
#pragma unroll
  for (int i = 0; i < 4; ++i) {
    int r = i * 16 + lrow; if (r > 48) r = 48;
    rr[i] = r;
  }

  float fu[4][16];

  for (int h = 0; h < NH; ++h) {
    f32x4 acc[4][4];   // [qt][kt]
#pragma unroll
    for (int qt = 0; qt < 4; ++qt)
#pragma unroll
      for (int kt = 0; kt < 4; ++kt) acc[qt][kt] = z4;

#pragma unroll
    for (int e = 0; e < 4; ++e) {
      long kf[4], qf[4];
#pragma unroll
      for (int kt = 0; kt < 4; ++kt)
        kf[kt] = *(const long*)(Kb + (size_t)rr[kt] * CQK + h * HD + e * 32 + lk);
#pragma unroll
      for (int qt = 0; qt < 4; ++qt)
        qf[qt] = *(const long*)(Qb + (size_t)rr[qt] * CQK + h * HD + e * 32 + lk);
#pragma unroll
      for (int qt = 0; qt < 4; ++qt)
#pragma unroll
        for (int kt = 0; kt < 4; ++kt)
          acc[qt][kt] = __builtin_amdgcn_mfma_f32_16x16x32_fp8_fp8(kf[kt], qf[qt],
                                                                   acc[qt][kt], 0, 0, 0);
    }

#pragma unroll
    for (int qt = 0; qt < 4; ++qt) {
      float mx = -1e30f;
#pragma unroll
      for (int kt = 0; kt < 4; ++kt)
#pragma unroll
        for (int r = 0; r < 4; ++r) {
          int k = kt * 16 + hi * 4 + r;
          if (k < N_) mx = fmaxf(mx, acc[qt][kt][r]);
        }
      mx = fmaxf(mx, __shfl_xor(mx, 16));
      mx = fmaxf(mx, __shfl_xor(mx, 32));
      float ev[16];
      float sum = 0.f;
#pragma unroll
      for (int kt = 0; kt < 4; ++kt)
#pragma unroll
        for (int r = 0; r < 4; ++r) {
          int k = kt * 16 + hi * 4 + r;
          float e = (k < N_) ? __expf(acc[qt][kt][r] - mx) : 0.f;
          ev[kt * 4 + r] = e;
          sum += e;
        }
      sum += __shfl_xor(sum, 16);
      sum += __shfl_xor(sum, 32);
      float rs = 1.0f / sum;
#pragma unroll
      for (int i = 0; i < 16; ++i) {
        float p = ev[i] * rs;
        fu[qt][i] = (h == 0) ? p : fminf(fu[qt][i], p);
      }
    }
  }

  // ---- bits with validity pad (+INF never selected/counted) ----
  u32 vb[4][16];
#pragma unroll
  for (int qt = 0; qt < 4; ++qt) {
    int q = qt * 16 + lrow;
#pragma unroll
    for (int i = 0; i < 16; ++i) {
      int k = (i >> 2) * 16 + hi * 4 + (i & 3);
      vb[qt][i] = (q < N_ && k < N_) ? __builtin_bit_cast(u32, fu[qt][i]) : 0x7F800000u;
    }
  }

  // ---- in-wave binary search: largest u with count(v < u) < KTOP ----
  u32 thr = 0;
  for (int bit = 29; bit >= 0; --bit) {
    u32 cand = thr | (1u << bit);
    int c = 0;
#pragma unroll
    for (int qt = 0; qt < 4; ++qt)
#pragma unroll
      for (int i = 0; i < 16; ++i) c += (vb[qt][i] < cand) ? 1 : 0;
    c += __shfl_xor(c, 1);  c += __shfl_xor(c, 2);  c += __shfl_xor(c, 4);
    c += __shfl_xor(c, 8);  c += __shfl_xor(c, 16); c += __shfl_xor(c, 32);
    if (c < KTOP) thr = cand;
  }

  // ---- membership -> block LDS mask ----
#pragma unroll
  for (int qt = 0; qt < 4; ++qt) {
    int q = qt * 16 + lrow;
#pragma unroll
    for (int i = 0; i < 16; ++i) {
      int k = (i >> 2) * 16 + hi * 4 + (i & 3);
      int p = q * N_ + k;
      if (q < N_ && k < N_ && p != 0 && vb[qt][i] <= thr)
        atomicOr(&lmask[p >> 5], 1u << (p & 31));
    }
  }

  // ---- rollout: rs over k (in-lane + hi), cs over q (in-lane qt + lrow) ----
  float rsv[4];
#pragma unroll
  for (int qt = 0; qt < 4; ++qt) {
    int q = qt * 16 + lrow;
    float s = 0.f;
#pragma unroll
    for (int i = 0; i < 16; ++i) {
      int k = (i >> 2) * 16 + hi * 4 + (i & 3);
      s += (q < N_ && k < N_) ? fu[qt][i] : 0.f;
    }
    s += __shfl_xor(s, 16); s += __shfl_xor(s, 32);
    rsv[qt] = s;
  }
  float csv[16];
#pragma unroll
  for (int i = 0; i < 16; ++i) {
    int k = (i >> 2) * 16 + hi * 4 + (i & 3);
    float s = 0.f;
#pragma unroll
    for (int qt = 0; qt < 4; ++qt) {
      int q = qt * 16 + lrow;
      s += (q < N_ && k < N_) ? fu[qt][i] : 0.f;
    }
    s += __shfl_xor(s, 1); s += __shfl_xor(s, 2);
    s += __shfl_xor(s, 4); s += __shfl_xor(s, 8);
    csv[i] = s;
  }
  // att[bg][t]: t = kt*16 + hi*4 + r; rs fetched from lane lrow = t%16
#pragma unroll
  for (int kt = 0; kt < 4; ++kt)
#pragma unroll
    for (int r = 0; r < 4; ++r) {
      int tt = kt * 16 + hi * 4 + r;
      float rv = __shfl(rsv[kt], hi * 4 + r);
      if (lrow == 0 && tt < N_)
        att[(size_t)bg * N_ + tt] = (csv[kt * 4 + r] + 1.0f) / (49.0f * (rv + 1.0f));
    }

  // ---- batch 0: spill fused values for the fixup kernel ----
  if (bg == 0) {
#pragma unroll
    for (int qt = 0; qt < 4; ++qt) {
      int q = qt * 16 + lrow;
#pragma unroll
      for (int i = 0; i < 16; ++i) {
        int k = (i >> 2) * 16 + hi * 4 + (i & 3);
        if (q < N_ && k < N_) fused0[q * N_ + k] = fu[qt][i];
      }
    }
  }

  __syncthreads();
  for (int p = tid; p < 76; p += 256)
    if (lmask[p]) atomicOr(&gmask[p], lmask[p]);
}

// ---------------- kernel 5: batch-0 fixup: apply union mask, redo rollout ----------------
__global__ void k_fix0(const float* __restrict__ fused0, const u32* __restrict__ gmask,
                       float* __restrict__ att) {
  __shared__ float fl[NN];
  const int t = threadIdx.x;
  for (int p = t; p < NN; p += 256) {
    float vv = fused0[p];
    if ((gmask[p >> 5] >> (p & 31)) & 1u) vv = 0.f;
    fl[p] = vv;
  }
  __syncthreads();
  if (t < N_) {
    float rs = 0.f, cs = 0.f;
    for (int m = 0; m < N_; ++m) { rs += fl[t * N_ + m]; cs += fl[m * N_ + t]; }
    att[t] = (cs + 1.0f) / (49.0f * (rs + 1.0f));
  }
}

// ---------------- kernel 6: rx = x * (1 + att[b,n]) ----------------
__global__ void k_rx(const float* __restrict__ x, const float* __restrict__ att,
                     float* __restrict__ out) {
  const int total4 = B_ * C_ * N_ / 4;
  for (int g = blockIdx.x * 256 + threadIdx.x; g < total4; g += gridDim.x * 256) {
    u32 e0 = (u32)g * 4u;
    u32 b = e0 / (u32)(C_ * N_);
    u32 r = e0 - b * (u32)(C_ * N_);
    u32 n = r % (u32)N_;
    const float4 xv = ((const float4*)x)[g];
    const float* ab = att + b * N_;
    float a0 = ab[n];
    u32 n1 = n + 1;  if (n1 == N_) n1 = 0;  float a1 = ab[n1];
    u32 n2 = n1 + 1; if (n2 == N_) n2 = 0;  float a2 = ab[n2];
    u32 n3 = n2 + 1; if (n3 == N_) n3 = 0;  float a3 = ab[n3];
    float4 o;
    o.x = xv.x * (1.f + a0); o.y = xv.y * (1.f + a1);
    o.z = xv.z * (1.f + a2); o.w = xv.w * (1.f + a3);
    ((float4*)out)[g] = o;
  }
}

extern "C" void kernel_launch(void* const* d_in, const int* in_sizes, int n_in,
                              void* d_out, int out_size, void* d_ws, size_t ws_size,
                              hipStream_t stream) {
  const float* x = (const float*)d_in[0];
  const float* W = (const float*)d_in[1];
  float* out = (float*)d_out;
  char* ws = (char*)d_ws;

  // group size G (batches per pass): multiples of 256 so MG % 128 == 0
  const size_t fixed = 200704 /*att*/ + 1605632 /*Wf8*/ + 1024 /*gmask*/ + 9632 /*fused0*/;
  int G = 256;
  const int cands[3] = {1024, 512, 256};
  for (int i = 0; i < 3; ++i) {
    if (fixed + (size_t)cands[i] * 49 * CQK <= ws_size) { G = cands[i]; break; }
  }

  const size_t qkbytes = (size_t)G * 49 * CQK;   // fp8: 1 B/el
  u8*       QKg    = (u8*)ws;
  float*    att    = (float*)(ws + qkbytes);
  u8*       Wf8    = (u8*)(ws + qkbytes + 200704);
  u32*      gmask  = (u32*)(ws + qkbytes + 200704 + 1605632);
  float*    fused0 = (float*)(ws + qkbytes + 200704 + 1605632 + 1024);
  u8*       tokens = (u8*)d_out;   // scratch (45 MB); d_out fully rewritten by k_rx

  hipMemsetAsync(gmask, 0, 76 * sizeof(u32), stream);
  k_convW<<<(CQK * C_ / 4 + 255) / 256, 256, 0, stream>>>(W, Wf8);

  const int ngroups = B_ / G;
  for (int g = 0; g < ngroups; ++g) {
    const int boff = g * G;
    const int MG = G * 49;
    const int mtc = MG / 128;
    k_tr<<<G * 14, 256, 0, stream>>>(x, tokens, boff);
    k_gemm<<<mtc * 14, 512, 0, stream>>>(tokens, Wf8, QKg, MG);
    k_attn2<<<G / 4, 256, 0, stream>>>(QKg, att, gmask, fused0, boff);
  }

  k_fix0<<<1, 256, 0, stream>>>(fused0, gmask, att);
  k_rx<<<4096, 256, 0, stream>>>(x, att, out);
}

// Round 19
// 284.887 us; speedup vs baseline: 1.2586x; 1.2586x over previous
//
#include <hip/hip_runtime.h>
#include <hip/hip_bf16.h>
#include <hip/hip_fp8.h>

#define B_    1024
#define C_    896
#define N_    49
#define NN    2401
#define HD    128
#define NH    7
#define CQK   1792      // q,k cols of QK (V never used)
#define KTOP  2160      // int(2401*0.9)
#define SCALE 0.08838834764831845f  // 128^-0.5

typedef unsigned short ushort_t;
typedef unsigned char u8;
typedef unsigned int u32;
typedef float f32x4  __attribute__((ext_vector_type(4)));
typedef int   i32x4  __attribute__((ext_vector_type(4)));
typedef int   i32x8  __attribute__((ext_vector_type(8)));

#define SCALE1 0x7F7F7F7F   // e8m0 = 127 in all bytes -> x1.0

__device__ __forceinline__ u8 f2fp8(float f) {
  __hip_fp8_e4m3 q(f);                      // OCP e4m3fn on gfx950
  return (u8)q.__x;
}

__device__ __forceinline__ void gload16(const void* g, void* l) {
  __builtin_amdgcn_global_load_lds((const __attribute__((address_space(1))) u32*)g,
                                   (__attribute__((address_space(3))) u32*)l, 16, 0, 0);
}

// ---------------- kernel 1: W (first 1792 rows) -> fp8 e4m3 ----------------
__global__ void k_convW(const float* __restrict__ W, u8* __restrict__ Wf8) {
  int i = blockIdx.x * 256 + threadIdx.x;          // quad index
  if (i >= CQK * C_ / 4) return;
  const float* wp = W + (size_t)i * 4;
  u32 r = (u32)f2fp8(wp[0]) | ((u32)f2fp8(wp[1]) << 8)
        | ((u32)f2fp8(wp[2]) << 16) | ((u32)f2fp8(wp[3]) << 24);
  ((u32*)Wf8)[i] = r;
}

// ---------------- kernel 2: transpose x -> tokens fp8 [MG][896] ----------------
__global__ __launch_bounds__(256) void k_tr(const float* __restrict__ x,
                                            u8* __restrict__ tokens,
                                            int boff) {
  __shared__ u8 T2[49][80];
  const int bid = blockIdx.x;
  const int bl  = bid / 14;            // local batch
  const int cg  = bid % 14;            // c-group (64 channels)
  const float* xb = x + (size_t)(boff + bl) * (C_ * N_) + (size_t)cg * 64 * N_;
  for (int idx = threadIdx.x; idx < 784; idx += 256) {   // 64*49/4 float4s
    float4 f = ((const float4*)xb)[idx];
    int e0 = idx * 4;
#pragma unroll
    for (int u = 0; u < 4; ++u) {
      int e = e0 + u;
      int ci = e / 49, n = e - ci * 49;
      float v = (u == 0) ? f.x : (u == 1) ? f.y : (u == 2) ? f.z : f.w;
      T2[n][ci] = f2fp8(v);
    }
  }
  __syncthreads();
  u8* tb = tokens + (size_t)(bl * 49) * C_ + cg * 64;
  for (int idx = threadIdx.x; idx < 49 * 4; idx += 256) {
    int n = idx >> 2, c16 = (idx & 3) * 16;
    *(uint4*)(tb + (size_t)n * C_ + c16) = *(const uint4*)&T2[n][c16];
  }
}

// ---------------- kernel 3: GEMM QK = tokens * Wf8^T (MX fp8, unit scales) ----------------
// 128x128 tile, BK=128, 8 waves (wm=w&1 M-half 64, wn=w>>1 N-quarter 32),
// wave-tile 64x32 -> acc only 32 f32/lane so launch_bounds(512,4) fits w/o spill.
// 2-slot STATIC 64 KB LDS -> 2 blocks/CU = 16 waves/CU = 4 waves/SIMD (TLP hides drain).
// mfma_scale_f32_16x16x128_f8f6f4, unit e8m0 scales (bit-identical to plain fp8).
// Swizzle: 16B piece phys = logical ^ (row&7); lane's 32B = phys p0 and p0^16.
__global__ __launch_bounds__(512, 4) void k_gemm(const u8* __restrict__ tokens,
                                                 const u8* __restrict__ Wf8,
                                                 u8* __restrict__ QK,
                                                 int MG) {
  __shared__ u8 sA[2][16384];   // [slot][128 rows][128 B]
  __shared__ u8 sB[2][16384];

  // bijective XCD-chunk swizzle (m204)
  const int nwg = gridDim.x;
  const int q8 = nwg >> 3, r8 = nwg & 7;
  const int xcd = blockIdx.x & 7, idx8 = blockIdx.x >> 3;
  const int tile = (xcd < r8 ? xcd * (q8 + 1) : r8 * (q8 + 1) + (xcd - r8) * q8) + idx8;

  const int mt = tile / 14, nt = tile - mt * 14;
  const int m0 = mt * 128, n0 = nt * 128;

  const int t = threadIdx.x;
  const int w = t >> 6, l = t & 63;
  const int lrow = l & 15, hi = l >> 4;
  const int wm = w & 1, wn = w >> 1;   // wm: M-half (64), wn: N-quarter (32)

  // stage-side: thread t covers rows (t>>3)+u*64, 16B piece (t&7), swizzled source
  const int srow8 = t >> 3;                        // 0..63
  const int sp16  = ((t & 7) ^ (srow8 & 7)) * 16;  // pre-swizzled source byte col
  const u8* aSrc[2];
  const u8* bSrc[2];
#pragma unroll
  for (int u = 0; u < 2; ++u) {
    int ar = m0 + u * 64 + srow8; if (ar >= MG) ar = MG - 1;
    aSrc[u] = tokens + (size_t)ar * C_ + sp16;
    bSrc[u] = Wf8 + (size_t)(n0 + u * 64 + srow8) * C_ + sp16;
  }
  u8* ldsA = &sA[0][0] + t * 16;
  u8* ldsB = &sB[0][0] + t * 16;

  // frag-side: lane's low 16B = logical piece 2hi -> phys p0; high 16B = p0^16
  const int key = lrow & 7;
  const int p0 = ((2 * hi) ^ key) * 16;
  const int aRow0 = (wm * 64 + lrow) * 128;   // + m*16*128
  const int bRow0 = (wn * 32 + lrow) * 128;   // + n*16*128

  f32x4 acc[4][2];
#pragma unroll
  for (int m = 0; m < 4; ++m)
#pragma unroll
    for (int n = 0; n < 2; ++n) acc[m][n] = (f32x4){0.f, 0.f, 0.f, 0.f};

  auto STAGE = [&](int kt) {
    const int so = (kt & 1) * 16384;
    const int kc = kt * 128;
#pragma unroll
    for (int u = 0; u < 2; ++u) {
      gload16(aSrc[u] + kc, ldsA + so + u * 8192);
      gload16(bSrc[u] + kc, ldsB + so + u * 8192);
    }
  };
  auto LD32 = [&](const u8* base) -> i32x8 {
    i32x8 v;
    *(i32x4*)&v       = *(const i32x4*)(base + p0);
    *((i32x4*)&v + 1) = *(const i32x4*)(base + (p0 ^ 16));
    return v;
  };

  STAGE(0);
  __syncthreads();

#pragma unroll 1
  for (int kt = 0; kt < 7; ++kt) {
    const int so = (kt & 1) * 16384;
    if (kt < 6) STAGE(kt + 1);
    i32x8 b8[2], av[4];
#pragma unroll
    for (int n = 0; n < 2; ++n)
      b8[n] = LD32(&sB[0][0] + so + bRow0 + n * 2048);
#pragma unroll
    for (int m = 0; m < 4; ++m)
      av[m] = LD32(&sA[0][0] + so + aRow0 + m * 2048);
    __builtin_amdgcn_s_setprio(1);
#pragma unroll
    for (int m = 0; m < 4; ++m)
#pragma unroll
      for (int n = 0; n < 2; ++n)
        acc[m][n] = __builtin_amdgcn_mfma_scale_f32_16x16x128_f8f6f4(
            av[m], b8[n], acc[m][n],
            0 /*cbsz: fp8*/, 0 /*blgp: fp8*/,
            0, SCALE1, 0, SCALE1);
    __builtin_amdgcn_s_setprio(0);
    __syncthreads();   // drain + barrier; other resident waves/blocks compute meanwhile
  }

  // epilogue: D col=lane&15, row=(lane>>4)*4+r; fold SCALE into Q cols (<896); QK fp8
#pragma unroll
  for (int m = 0; m < 4; ++m) {
#pragma unroll
    for (int n = 0; n < 2; ++n) {
      int gcol = n0 + wn * 32 + n * 16 + lrow;
      float sc = (gcol < C_) ? SCALE : 1.0f;
#pragma unroll
      for (int r = 0; r < 4; ++r) {
        int grow = m0 + wm * 64 + m * 16 + hi * 4 + r;
        if (grow < MG)
          QK[(size_t)grow * CQK + gcol] = f2fp8(acc[m][n][r] * sc);
      }
    }
  }
}

// ---------------- kernel 4: logits+softmax+min+select+rollout, one WAVE per batch ----------------
__global__ __launch_bounds__(256) void k_attn2(const u8* __restrict__ QK,
                                               float* __restrict__ att,
                                               u32* __restrict__ gmask,
                                               float* __restrict__ fused0,
                                               int boff) {
  __shared__ u32 lmask[76];
  const int tid  = threadIdx.x;
  const int wid  = tid >> 6;
  const int lane = tid & 63;
  const int lrow = lane & 15;
  const int hi   = lane >> 4;
  const int lk   = hi * 8;
  const int bloc = blockIdx.x * 4 + wid;
  const int bg   = boff + bloc;
  const f32x4 z4 = {0.f, 0.f, 0.f, 0.f};

  for (int p = tid; p < 76; p += 256) lmask[p] = 0u;
  __syncthreads();

  const u8* Qb = QK + (size_t)bloc * 49 * CQK;
  const u8* Kb = Qb + C_;

  int rr[4];
#pragma unroll
  for (int i = 0; i < 4; ++i) {
    int r = i * 16 + lrow; if (r > 48) r = 48;
    rr[i] = r;
  }

  float fu[4][16];

  for (int h = 0; h < NH; ++h) {
    f32x4 acc[4][4];   // [qt][kt]
#pragma unroll
    for (int qt = 0; qt < 4; ++qt)
#pragma unroll
      for (int kt = 0; kt < 4; ++kt) acc[qt][kt] = z4;

#pragma unroll
    for (int e = 0; e < 4; ++e) {
      long kf[4], qf[4];
#pragma unroll
      for (int kt = 0; kt < 4; ++kt)
        kf[kt] = *(const long*)(Kb + (size_t)rr[kt] * CQK + h * HD + e * 32 + lk);
#pragma unroll
      for (int qt = 0; qt < 4; ++qt)
        qf[qt] = *(const long*)(Qb + (size_t)rr[qt] * CQK + h * HD + e * 32 + lk);
#pragma unroll
      for (int qt = 0; qt < 4; ++qt)
#pragma unroll
        for (int kt = 0; kt < 4; ++kt)
          acc[qt][kt] = __builtin_amdgcn_mfma_f32_16x16x32_fp8_fp8(kf[kt], qf[qt],
                                                                   acc[qt][kt], 0, 0, 0);
    }

#pragma unroll
    for (int qt = 0; qt < 4; ++qt) {
      float mx = -1e30f;
#pragma unroll
      for (int kt = 0; kt < 4; ++kt)
#pragma unroll
        for (int r = 0; r < 4; ++r) {
          int k = kt * 16 + hi * 4 + r;
          if (k < N_) mx = fmaxf(mx, acc[qt][kt][r]);
        }
      mx = fmaxf(mx, __shfl_xor(mx, 16));
      mx = fmaxf(mx, __shfl_xor(mx, 32));
      float ev[16];
      float sum = 0.f;
#pragma unroll
      for (int kt = 0; kt < 4; ++kt)
#pragma unroll
        for (int r = 0; r < 4; ++r) {
          int k = kt * 16 + hi * 4 + r;
          float e = (k < N_) ? __expf(acc[qt][kt][r] - mx) : 0.f;
          ev[kt * 4 + r] = e;
          sum += e;
        }
      sum += __shfl_xor(sum, 16);
      sum += __shfl_xor(sum, 32);
      float rs = 1.0f / sum;
#pragma unroll
      for (int i = 0; i < 16; ++i) {
        float p = ev[i] * rs;
        fu[qt][i] = (h == 0) ? p : fminf(fu[qt][i], p);
      }
    }
  }

  // ---- bits with validity pad (+INF never selected/counted) ----
  u32 vb[4][16];
#pragma unroll
  for (int qt = 0; qt < 4; ++qt) {
    int q = qt * 16 + lrow;
#pragma unroll
    for (int i = 0; i < 16; ++i) {
      int k = (i >> 2) * 16 + hi * 4 + (i & 3);
      vb[qt][i] = (q < N_ && k < N_) ? __builtin_bit_cast(u32, fu[qt][i]) : 0x7F800000u;
    }
  }

  // ---- in-wave binary search: largest u with count(v < u) < KTOP ----
  u32 thr = 0;
  for (int bit = 29; bit >= 0; --bit) {
    u32 cand = thr | (1u << bit);
    int c = 0;
#pragma unroll
    for (int qt = 0; qt < 4; ++qt)
#pragma unroll
      for (int i = 0; i < 16; ++i) c += (vb[qt][i] < cand) ? 1 : 0;
    c += __shfl_xor(c, 1);  c += __shfl_xor(c, 2);  c += __shfl_xor(c, 4);
    c += __shfl_xor(c, 8);  c += __shfl_xor(c, 16); c += __shfl_xor(c, 32);
    if (c < KTOP) thr = cand;
  }

  // ---- membership -> block LDS mask ----
#pragma unroll
  for (int qt = 0; qt < 4; ++qt) {
    int q = qt * 16 + lrow;
#pragma unroll
    for (int i = 0; i < 16; ++i) {
      int k = (i >> 2) * 16 + hi * 4 + (i & 3);
      int p = q * N_ + k;
      if (q < N_ && k < N_ && p != 0 && vb[qt][i] <= thr)
        atomicOr(&lmask[p >> 5], 1u << (p & 31));
    }
  }

  // ---- rollout: rs over k (in-lane + hi), cs over q (in-lane qt + lrow) ----
  float rsv[4];
#pragma unroll
  for (int qt = 0; qt < 4; ++qt) {
    int q = qt * 16 + lrow;
    float s = 0.f;
#pragma unroll
    for (int i = 0; i < 16; ++i) {
      int k = (i >> 2) * 16 + hi * 4 + (i & 3);
      s += (q < N_ && k < N_) ? fu[qt][i] : 0.f;
    }
    s += __shfl_xor(s, 16); s += __shfl_xor(s, 32);
    rsv[qt] = s;
  }
  float csv[16];
#pragma unroll
  for (int i = 0; i < 16; ++i) {
    int k = (i >> 2) * 16 + hi * 4 + (i & 3);
    float s = 0.f;
#pragma unroll
    for (int qt = 0; qt < 4; ++qt) {
      int q = qt * 16 + lrow;
      s += (q < N_ && k < N_) ? fu[qt][i] : 0.f;
    }
    s += __shfl_xor(s, 1); s += __shfl_xor(s, 2);
    s += __shfl_xor(s, 4); s += __shfl_xor(s, 8);
    csv[i] = s;
  }
  // att[bg][t]: t = kt*16 + hi*4 + r; rs fetched from lane lrow = t%16
#pragma unroll
  for (int kt = 0; kt < 4; ++kt)
#pragma unroll
    for (int r = 0; r < 4; ++r) {
      int tt = kt * 16 + hi * 4 + r;
      float rv = __shfl(rsv[kt], hi * 4 + r);
      if (lrow == 0 && tt < N_)
        att[(size_t)bg * N_ + tt] = (csv[kt * 4 + r] + 1.0f) / (49.0f * (rv + 1.0f));
    }

  // ---- batch 0: spill fused values for the fixup kernel ----
  if (bg == 0) {
#pragma unroll
    for (int qt = 0; qt < 4; ++qt) {
      int q = qt * 16 + lrow;
#pragma unroll
      for (int i = 0; i < 16; ++i) {
        int k = (i >> 2) * 16 + hi * 4 + (i & 3);
        if (q < N_ && k < N_) fused0[q * N_ + k] = fu[qt][i];
      }
    }
  }

  __syncthreads();
  for (int p = tid; p < 76; p += 256)
    if (lmask[p]) atomicOr(&gmask[p], lmask[p]);
}

// ---------------- kernel 5: batch-0 fixup: apply union mask, redo rollout ----------------
__global__ void k_fix0(const float* __restrict__ fused0, const u32* __restrict__ gmask,
                       float* __restrict__ att) {
  __shared__ float fl[NN];
  const int t = threadIdx.x;
  for (int p = t; p < NN; p += 256) {
    float vv = fused0[p];
    if ((gmask[p >> 5] >> (p & 31)) & 1u) vv = 0.f;
    fl[p] = vv;
  }
  __syncthreads();
  if (t < N_) {
    float rs = 0.f, cs = 0.f;
    for (int m = 0; m < N_; ++m) { rs += fl[t * N_ + m]; cs += fl[m * N_ + t]; }
    att[t] = (cs + 1.0f) / (49.0f * (rs + 1.0f));
  }
}

// ---------------- kernel 6: rx = x * (1 + att[b,n]) ----------------
__global__ void k_rx(const float* __restrict__ x, const float* __restrict__ att,
                     float* __restrict__ out) {
  const int total4 = B_ * C_ * N_ / 4;
  for (int g = blockIdx.x * 256 + threadIdx.x; g < total4; g += gridDim.x * 256) {
    u32 e0 = (u32)g * 4u;
    u32 b = e0 / (u32)(C_ * N_);
    u32 r = e0 - b * (u32)(C_ * N_);
    u32 n = r % (u32)N_;
    const float4 xv = ((const float4*)x)[g];
    const float* ab = att + b * N_;
    float a0 = ab[n];
    u32 n1 = n + 1;  if (n1 == N_) n1 = 0;  float a1 = ab[n1];
    u32 n2 = n1 + 1; if (n2 == N_) n2 = 0;  float a2 = ab[n2];
    u32 n3 = n2 + 1; if (n3 == N_) n3 = 0;  float a3 = ab[n3];
    float4 o;
    o.x = xv.x * (1.f + a0); o.y = xv.y * (1.f + a1);
    o.z = xv.z * (1.f + a2); o.w = xv.w * (1.f + a3);
    ((float4*)out)[g] = o;
  }
}

extern "C" void kernel_launch(void* const* d_in, const int* in_sizes, int n_in,
                              void* d_out, int out_size, void* d_ws, size_t ws_size,
                              hipStream_t stream) {
  const float* x = (const float*)d_in[0];
  const float* W = (const float*)d_in[1];
  float* out = (float*)d_out;
  char* ws = (char*)d_ws;

  // group size G (batches per pass): multiples of 256 so MG % 128 == 0
  const size_t fixed = 200704 /*att*/ + 1605632 /*Wf8*/ + 1024 /*gmask*/ + 9632 /*fused0*/;
  int G = 256;
  const int cands[3] = {1024, 512, 256};
  for (int i = 0; i < 3; ++i) {
    if (fixed + (size_t)cands[i] * 49 * CQK <= ws_size) { G = cands[i]; break; }
  }

  const size_t qkbytes = (size_t)G * 49 * CQK;   // fp8: 1 B/el
  u8*       QKg    = (u8*)ws;
  float*    att    = (float*)(ws + qkbytes);
  u8*       Wf8    = (u8*)(ws + qkbytes + 200704);
  u32*      gmask  = (u32*)(ws + qkbytes + 200704 + 1605632);
  float*    fused0 = (float*)(ws + qkbytes + 200704 + 1605632 + 1024);
  u8*       tokens = (u8*)d_out;   // scratch (45 MB); d_out fully rewritten by k_rx

  hipMemsetAsync(gmask, 0, 76 * sizeof(u32), stream);
  k_convW<<<(CQK * C_ / 4 + 255) / 256, 256, 0, stream>>>(W, Wf8);

  const int ngroups = B_ / G;
  for (int g = 0; g < ngroups; ++g) {
    const int boff = g * G;
    const int MG = G * 49;
    const int mtc = MG / 128;
    k_tr<<<G * 14, 256, 0, stream>>>(x, tokens, boff);
    k_gemm<<<mtc * 14, 512, 0, stream>>>(tokens, Wf8, QKg, MG);
    k_attn2<<<G / 4, 256, 0, stream>>>(QKg, att, gmask, fused0, boff);
  }

  k_fix0<<<1, 256, 0, stream>>>(fused0, gmask, att);
  k_rx<<<4096, 256, 0, stream>>>(x, att, out);
}